// Round 3
// baseline (1045.330 us; speedup 1.0000x reference)
//
#include <hip/hip_runtime.h>
#include <hip/hip_bf16.h>

#define IN_DIM 500
#define HID 128
#define OUTD 40

static __device__ __forceinline__ float rsqrt_acc(float x) {
  // rsqrt + one Newton step -> ~fp32-exact (matches jax.lax.rsqrt within tolerance)
  float r = rsqrtf(x);
  return r * (1.5f - 0.5f * x * r * r);
}

// ---- zero-fill (replaces hipMemsetAsync: strictly graph-capture-safe) ----
__global__ void zero_kernel(int* __restrict__ p, int n) {
  int i = blockIdx.x * 256 + threadIdx.x;
  if (i < n) p[i] = 0;
}

// ---- degree histogram over dst (edges only; self-loop added in dinv) ----
__global__ void hist_kernel(const int* __restrict__ dst, int* __restrict__ deg, int E) {
  int e = blockIdx.x * 256 + threadIdx.x;
  if (e < E) atomicAdd(&deg[dst[e]], 1);
}

__global__ void dinv_kernel(const int* __restrict__ deg, float* __restrict__ dinv, int N) {
  int n = blockIdx.x * 256 + threadIdx.x;
  if (n < N) dinv[n] = rsqrt_acc((float)deg[n] + 1.0f);
}

// ---- two-level exclusive scan of deg -> row_ptr (N up to 256*1024) ----
__global__ void scan_a(const int* __restrict__ deg, int* __restrict__ partial,
                       int* __restrict__ blockSums, int N) {
  __shared__ int sums[256];
  int t = threadIdx.x;
  int base = blockIdx.x * 1024 + t * 4;
  int v0 = (base + 0) < N ? deg[base + 0] : 0;
  int v1 = (base + 1) < N ? deg[base + 1] : 0;
  int v2 = (base + 2) < N ? deg[base + 2] : 0;
  int v3 = (base + 3) < N ? deg[base + 3] : 0;
  int l0 = v0, l1 = l0 + v1, l2 = l1 + v2, l3 = l2 + v3;
  sums[t] = l3;
  __syncthreads();
  for (int o = 1; o < 256; o <<= 1) {
    int a = sums[t];
    int b = (t >= o) ? sums[t - o] : 0;
    __syncthreads();
    sums[t] = a + b;
    __syncthreads();
  }
  int excl = sums[t] - l3;  // sum of all previous threads in block
  if (t == 0) blockSums[blockIdx.x] = sums[255];
  if (base + 0 < N) partial[base + 0] = excl;
  if (base + 1 < N) partial[base + 1] = excl + l0;
  if (base + 2 < N) partial[base + 2] = excl + l1;
  if (base + 3 < N) partial[base + 3] = excl + l2;
}

__global__ void scan_b(int* __restrict__ blockSums, int nb) {
  __shared__ int s[256];
  int t = threadIdx.x;
  int orig = (t < nb) ? blockSums[t] : 0;   // guard: slots >= nb are 0xAA poison
  s[t] = orig;
  __syncthreads();
  for (int o = 1; o < 256; o <<= 1) {
    int a = s[t];
    int b = (t >= o) ? s[t - o] : 0;
    __syncthreads();
    s[t] = a + b;
    __syncthreads();
  }
  if (t < nb) blockSums[t] = s[t] - orig;  // exclusive block offsets, in place
}

__global__ void scan_c(int* __restrict__ row_ptr, const int* __restrict__ blockOff,
                       int* __restrict__ cursor, int N, int E) {
  int n = blockIdx.x * 256 + threadIdx.x;
  if (n < N) {
    int v = row_ptr[n] + blockOff[n >> 10];
    row_ptr[n] = v;
    cursor[n] = v;
  }
  if (n == 0 && blockIdx.x == 0) row_ptr[N] = E;
}

// ---- CSR placement: counting-sort edges by dst; precompute edge norm ----
__global__ void place_kernel(const int* __restrict__ src, const int* __restrict__ dst,
                             const float* __restrict__ dinv, int* __restrict__ cursor,
                             int* __restrict__ eSrc, float* __restrict__ eW, int E) {
  int e = blockIdx.x * 256 + threadIdx.x;
  if (e < E) {
    int s = src[e], d = dst[e];
    int pos = atomicAdd(&cursor[d], 1);
    eSrc[pos] = s;
    eW[pos] = dinv[s] * dinv[d];
  }
}

// ---- GEMM1: H1[N,128] = X[N,500] @ W1[500,128], fp32 vector ----
// block = 256 threads, tile 64 rows x 128 cols, K chunk 20 (500 = 25*20)
__global__ __launch_bounds__(256) void gemm1_kernel(const float* __restrict__ X,
                                                    const float* __restrict__ W1,
                                                    float* __restrict__ H1, int N) {
  __shared__ float sA[20 * 68];   // transposed [k][row], pad 68 to spread banks
  __shared__ float sB[20 * 128];  // [k][col]
  const int t = threadIdx.x;
  const int rowBase = blockIdx.x * 64;
  const int trow = t >> 5;  // 0..7 -> rows trow*8 .. +8
  const int tcol = t & 31;  // 0..31 -> cols tcol*4 .. +4

  float4 acc[8];
#pragma unroll
  for (int i = 0; i < 8; i++) acc[i] = make_float4(0.f, 0.f, 0.f, 0.f);

  const int ar = t >> 2;         // staging row 0..63
  const int aj = (t & 3) * 5;    // staging k-offset 0,5,10,15
  const bool arOK = (rowBase + ar) < N;
  const float* xrow = X + (size_t)(rowBase + (arOK ? ar : 0)) * IN_DIM;

  for (int k0 = 0; k0 < IN_DIM; k0 += 20) {
    // stage A (transposed)
#pragma unroll
    for (int jj = 0; jj < 5; jj++) {
      int j = aj + jj;
      sA[j * 68 + ar] = arOK ? xrow[k0 + j] : 0.f;
    }
    // stage B: rows k0..k0+19 of W1 are 2560 contiguous floats
    const float4* bsrc = (const float4*)(W1 + (size_t)k0 * HID);
    for (int f = t; f < 640; f += 256) ((float4*)sB)[f] = bsrc[f];
    __syncthreads();

#pragma unroll 5
    for (int kk = 0; kk < 20; kk++) {
      float4 b = *(const float4*)&sB[kk * HID + tcol * 4];
      float4 a0 = *(const float4*)&sA[kk * 68 + trow * 8];
      float4 a1 = *(const float4*)&sA[kk * 68 + trow * 8 + 4];
#define FMA4(ac, s) ac.x += (s) * b.x; ac.y += (s) * b.y; ac.z += (s) * b.z; ac.w += (s) * b.w;
      FMA4(acc[0], a0.x) FMA4(acc[1], a0.y) FMA4(acc[2], a0.z) FMA4(acc[3], a0.w)
      FMA4(acc[4], a1.x) FMA4(acc[5], a1.y) FMA4(acc[6], a1.z) FMA4(acc[7], a1.w)
#undef FMA4
    }
    __syncthreads();
  }
#pragma unroll
  for (int i = 0; i < 8; i++) {
    int r = rowBase + trow * 8 + i;
    if (r < N) *(float4*)&H1[(size_t)r * HID + tcol * 4] = acc[i];
  }
}

// ---- agg1: thread per (node,col); CSR gather + self-loop + bias + ReLU ----
__global__ void agg1_kernel(const float* __restrict__ h1, const int* __restrict__ row_ptr,
                            const int* __restrict__ eSrc, const float* __restrict__ eW,
                            const float* __restrict__ dinv, const float* __restrict__ b1,
                            float* __restrict__ hrelu, int N) {
  int gid = blockIdx.x * 256 + threadIdx.x;
  int n = gid >> 7, c = gid & 127;
  if (n >= N) return;
  float di = dinv[n];
  float acc = h1[n * HID + c] * di * di;  // self-loop, norm = 1/deg
  int s0 = row_ptr[n], s1 = row_ptr[n + 1];
  for (int i = s0; i < s1; i++) acc += h1[eSrc[i] * HID + c] * eW[i];
  float v = acc + b1[c];
  hrelu[n * HID + c] = v > 0.f ? v : 0.f;
}

// ---- GEMM2: H2[N,40] = hrelu[N,128] @ W2[128,40] ----
// block 256, 64 rows; W2 zero-padded to 48 cols in LDS for aligned float4 strips
__global__ __launch_bounds__(256) void gemm2_kernel(const float* __restrict__ A,
                                                    const float* __restrict__ W2,
                                                    float* __restrict__ H2, int N) {
  __shared__ float tA[64 * 129];   // pad 129: read bank = (row+k)%32 -> broadcast-only
  __shared__ float w2s[128 * 48];
  const int t = threadIdx.x;
  const int rowBase = blockIdx.x * 64;
  for (int idx = t; idx < 128 * 48; idx += 256) {
    int k = idx / 48, c = idx - k * 48;
    w2s[idx] = (c < OUTD) ? W2[k * OUTD + c] : 0.f;
  }
  for (int f = t; f < 2048; f += 256) {
    int row = f >> 5, c4 = (f & 31) * 4;
    float4 v = make_float4(0.f, 0.f, 0.f, 0.f);
    if (rowBase + row < N) v = *(const float4*)&A[(size_t)(rowBase + row) * HID + c4];
    tA[row * 129 + c4 + 0] = v.x;
    tA[row * 129 + c4 + 1] = v.y;
    tA[row * 129 + c4 + 2] = v.z;
    tA[row * 129 + c4 + 3] = v.w;
  }
  __syncthreads();
  const int row = t >> 2;          // 0..63 (4 lanes share a row -> LDS broadcast)
  const int c0 = (t & 3) * 12;     // 12-col strip
  float acc[12];
#pragma unroll
  for (int j = 0; j < 12; j++) acc[j] = 0.f;
  for (int k = 0; k < HID; k++) {
    float a = tA[row * 129 + k];
    const float* bp = &w2s[k * 48 + c0];
#pragma unroll
    for (int j = 0; j < 12; j++) acc[j] += a * bp[j];
  }
  int r = rowBase + row;
  if (r < N) {
#pragma unroll
    for (int j = 0; j < 12; j++) {
      int c = c0 + j;
      if (c < OUTD) H2[(size_t)r * OUTD + c] = acc[j];
    }
  }
}

// ---- agg2: thread per (node,col) at 40 dims; + bias (no relu) -> d_out ----
__global__ void agg2_kernel(const float* __restrict__ h2, const int* __restrict__ row_ptr,
                            const int* __restrict__ eSrc, const float* __restrict__ eW,
                            const float* __restrict__ dinv, const float* __restrict__ b2,
                            float* __restrict__ out, int N) {
  int gid = blockIdx.x * 256 + threadIdx.x;
  int n = gid / OUTD;
  int c = gid - n * OUTD;
  if (n >= N) return;
  float di = dinv[n];
  float acc = h2[n * OUTD + c] * di * di;
  int s0 = row_ptr[n], s1 = row_ptr[n + 1];
  for (int i = s0; i < s1; i++) acc += h2[eSrc[i] * OUTD + c] * eW[i];
  out[n * OUTD + c] = acc + b2[c];
}

// ---- log_softmax over 40 cols, in place on d_out ----
__global__ void lsm_kernel(float* __restrict__ out, int N) {
  int n = blockIdx.x * 256 + threadIdx.x;
  if (n >= N) return;
  float* row = out + (size_t)n * OUTD;
  float v[OUTD];
  float m = -3.4e38f;
#pragma unroll
  for (int j = 0; j < OUTD; j++) {
    v[j] = row[j];
    m = fmaxf(m, v[j]);
  }
  float s = 0.f;
#pragma unroll
  for (int j = 0; j < OUTD; j++) s += expf(v[j] - m);
  float lse = m + logf(s);
#pragma unroll
  for (int j = 0; j < OUTD; j++) row[j] = v[j] - lse;
}

extern "C" void kernel_launch(void* const* d_in, const int* in_sizes, int n_in,
                              void* d_out, int out_size, void* d_ws, size_t ws_size,
                              hipStream_t stream) {
  const float* x  = (const float*)d_in[0];
  const int*   ei = (const int*)d_in[1];
  const float* W1 = (const float*)d_in[2];
  const float* b1 = (const float*)d_in[3];
  const float* W2 = (const float*)d_in[4];
  const float* b2 = (const float*)d_in[5];
  float* out = (float*)d_out;

  const int N = in_sizes[0] / IN_DIM;
  const int E = in_sizes[1] / 2;
  const int* src = ei;       // edge_index[0]
  const int* dst = ei + E;   // edge_index[1]

  // workspace layout (1KB-aligned): ~116 MB peak
  char* wsb = (char*)d_ws;
  size_t off = 0;
  auto alloc = [&](size_t bytes) -> char* {
    char* p = wsb + off;
    off = (off + bytes + 1023) & ~(size_t)1023;
    return p;
  };
  int*   deg       = (int*)alloc((size_t)N * 4);
  float* dinv      = (float*)alloc((size_t)N * 4);
  int*   blockSums = (int*)alloc(1024);
  int*   row_ptr   = (int*)alloc((size_t)(N + 1) * 4);
  int*   cursor    = (int*)alloc((size_t)N * 4);
  int*   eSrc      = (int*)alloc((size_t)E * 4);
  float* eW        = (float*)alloc((size_t)E * 4);
  float* h1        = (float*)alloc((size_t)N * HID * 4);
  float* hrelu     = (float*)alloc((size_t)N * HID * 4);
  float* h2        = h1;  // h1 dead after agg1; alias to cut peak ws usage
  (void)n_in; (void)out_size;

  // Workspace guard: if d_ws is too small, launching would OOB-write and
  // hard-crash the container. Bail (visible correctness failure) instead.
  if (off > ws_size) return;

  const int gE = (E + 255) / 256;
  const int gN = (N + 255) / 256;
  const int nb = (N + 1023) / 1024;
  const int gRows = (N + 63) / 64;

  zero_kernel<<<gN, 256, 0, stream>>>(deg, N);
  hist_kernel<<<gE, 256, 0, stream>>>(dst, deg, E);
  dinv_kernel<<<gN, 256, 0, stream>>>(deg, dinv, N);
  scan_a<<<nb, 256, 0, stream>>>(deg, row_ptr, blockSums, N);
  scan_b<<<1, 256, 0, stream>>>(blockSums, nb);
  scan_c<<<gN, 256, 0, stream>>>(row_ptr, blockSums, cursor, N, E);
  place_kernel<<<gE, 256, 0, stream>>>(src, dst, dinv, cursor, eSrc, eW, E);

  gemm1_kernel<<<gRows, 256, 0, stream>>>(x, W1, h1, N);
  agg1_kernel<<<(N * HID + 255) / 256, 256, 0, stream>>>(h1, row_ptr, eSrc, eW, dinv, b1, hrelu, N);
  gemm2_kernel<<<gRows, 256, 0, stream>>>(hrelu, W2, h2, N);
  agg2_kernel<<<(N * OUTD + 255) / 256, 256, 0, stream>>>(h2, row_ptr, eSrc, eW, dinv, b2, out, N);
  lsm_kernel<<<gN, 256, 0, stream>>>(out, N);
}

// Round 4
// 845.117 us; speedup vs baseline: 1.2369x; 1.2369x over previous
//
#include <hip/hip_runtime.h>
#include <hip/hip_bf16.h>

#define IN_DIM 500
#define HID 128
#define OUTD 40

static __device__ __forceinline__ float rsqrt_acc(float x) {
  // rsqrt + one Newton step -> ~fp32-exact (matches jax.lax.rsqrt within tolerance)
  float r = rsqrtf(x);
  return r * (1.5f - 0.5f * x * r * r);
}

// ---- zero-fill (replaces hipMemsetAsync: strictly graph-capture-safe) ----
__global__ void zero_kernel(int* __restrict__ p, int n) {
  int i = blockIdx.x * 256 + threadIdx.x;
  if (i < n) p[i] = 0;
}

// ---- degree histogram over dst (edges only; self-loop added in dinv) ----
__global__ void hist_kernel(const int* __restrict__ dst, int* __restrict__ deg, int E) {
  int e = blockIdx.x * 256 + threadIdx.x;
  if (e < E) atomicAdd(&deg[dst[e]], 1);
}

__global__ void dinv_kernel(const int* __restrict__ deg, float* __restrict__ dinv, int N) {
  int n = blockIdx.x * 256 + threadIdx.x;
  if (n < N) dinv[n] = rsqrt_acc((float)deg[n] + 1.0f);
}

// ---- two-level exclusive scan of deg -> row_ptr (N up to 256*1024) ----
__global__ void scan_a(const int* __restrict__ deg, int* __restrict__ partial,
                       int* __restrict__ blockSums, int N) {
  __shared__ int sums[256];
  int t = threadIdx.x;
  int base = blockIdx.x * 1024 + t * 4;
  int v0 = (base + 0) < N ? deg[base + 0] : 0;
  int v1 = (base + 1) < N ? deg[base + 1] : 0;
  int v2 = (base + 2) < N ? deg[base + 2] : 0;
  int v3 = (base + 3) < N ? deg[base + 3] : 0;
  int l0 = v0, l1 = l0 + v1, l2 = l1 + v2, l3 = l2 + v3;
  sums[t] = l3;
  __syncthreads();
  for (int o = 1; o < 256; o <<= 1) {
    int a = sums[t];
    int b = (t >= o) ? sums[t - o] : 0;
    __syncthreads();
    sums[t] = a + b;
    __syncthreads();
  }
  int excl = sums[t] - l3;  // sum of all previous threads in block
  if (t == 0) blockSums[blockIdx.x] = sums[255];
  if (base + 0 < N) partial[base + 0] = excl;
  if (base + 1 < N) partial[base + 1] = excl + l0;
  if (base + 2 < N) partial[base + 2] = excl + l1;
  if (base + 3 < N) partial[base + 3] = excl + l2;
}

__global__ void scan_b(int* __restrict__ blockSums, int nb) {
  __shared__ int s[256];
  int t = threadIdx.x;
  int orig = (t < nb) ? blockSums[t] : 0;   // guard: slots >= nb are 0xAA poison
  s[t] = orig;
  __syncthreads();
  for (int o = 1; o < 256; o <<= 1) {
    int a = s[t];
    int b = (t >= o) ? s[t - o] : 0;
    __syncthreads();
    s[t] = a + b;
    __syncthreads();
  }
  if (t < nb) blockSums[t] = s[t] - orig;  // exclusive block offsets, in place
}

__global__ void scan_c(int* __restrict__ row_ptr, const int* __restrict__ blockOff,
                       int* __restrict__ cursor, int N, int E) {
  int n = blockIdx.x * 256 + threadIdx.x;
  if (n < N) {
    int v = row_ptr[n] + blockOff[n >> 10];
    row_ptr[n] = v;
    cursor[n] = v;
  }
  if (n == 0 && blockIdx.x == 0) row_ptr[N] = E;
}

// ---- CSR placement: counting-sort edges by dst; precompute edge norm ----
__global__ void place_kernel(const int* __restrict__ src, const int* __restrict__ dst,
                             const float* __restrict__ dinv, int* __restrict__ cursor,
                             int* __restrict__ eSrc, float* __restrict__ eW, int E) {
  int e = blockIdx.x * 256 + threadIdx.x;
  if (e < E) {
    int s = src[e], d = dst[e];
    int pos = atomicAdd(&cursor[d], 1);
    eSrc[pos] = s;
    eW[pos] = dinv[s] * dinv[d];
  }
}

// ---- GEMM1: H1[N,128] = X[N,500] @ W1[500,128], fp32 vector ----
// block = 256 threads, tile 64 rows x 128 cols, K chunk 20 (500 = 25*20)
__global__ __launch_bounds__(256) void gemm1_kernel(const float* __restrict__ X,
                                                    const float* __restrict__ W1,
                                                    float* __restrict__ H1, int N) {
  __shared__ float sA[20 * 68];   // transposed [k][row], pad 68 to spread banks
  __shared__ float sB[20 * 128];  // [k][col]
  const int t = threadIdx.x;
  const int rowBase = blockIdx.x * 64;
  const int trow = t >> 5;  // 0..7 -> rows trow*8 .. +8
  const int tcol = t & 31;  // 0..31 -> cols tcol*4 .. +4

  float4 acc[8];
#pragma unroll
  for (int i = 0; i < 8; i++) acc[i] = make_float4(0.f, 0.f, 0.f, 0.f);

  const int ar = t >> 2;         // staging row 0..63
  const int aj = (t & 3) * 5;    // staging k-offset 0,5,10,15
  const bool arOK = (rowBase + ar) < N;
  const float* xrow = X + (size_t)(rowBase + (arOK ? ar : 0)) * IN_DIM;

  for (int k0 = 0; k0 < IN_DIM; k0 += 20) {
    // stage A (transposed)
#pragma unroll
    for (int jj = 0; jj < 5; jj++) {
      int j = aj + jj;
      sA[j * 68 + ar] = arOK ? xrow[k0 + j] : 0.f;
    }
    // stage B: rows k0..k0+19 of W1 are 2560 contiguous floats
    const float4* bsrc = (const float4*)(W1 + (size_t)k0 * HID);
    for (int f = t; f < 640; f += 256) ((float4*)sB)[f] = bsrc[f];
    __syncthreads();

#pragma unroll 5
    for (int kk = 0; kk < 20; kk++) {
      float4 b = *(const float4*)&sB[kk * HID + tcol * 4];
      float4 a0 = *(const float4*)&sA[kk * 68 + trow * 8];
      float4 a1 = *(const float4*)&sA[kk * 68 + trow * 8 + 4];
#define FMA4(ac, s) ac.x += (s) * b.x; ac.y += (s) * b.y; ac.z += (s) * b.z; ac.w += (s) * b.w;
      FMA4(acc[0], a0.x) FMA4(acc[1], a0.y) FMA4(acc[2], a0.z) FMA4(acc[3], a0.w)
      FMA4(acc[4], a1.x) FMA4(acc[5], a1.y) FMA4(acc[6], a1.z) FMA4(acc[7], a1.w)
#undef FMA4
    }
    __syncthreads();
  }
#pragma unroll
  for (int i = 0; i < 8; i++) {
    int r = rowBase + trow * 8 + i;
    if (r < N) *(float4*)&H1[(size_t)r * HID + tcol * 4] = acc[i];
  }
}

// ---- agg1 v2: thread per (node, col-group-of-4); float4 gather, 4-edge unroll ----
// MLP fix: 8 independent loads in flight per iteration vs 1 dependent chain.
__global__ void agg1_kernel(const float* __restrict__ h1, const int* __restrict__ row_ptr,
                            const int* __restrict__ eSrc, const float* __restrict__ eW,
                            const float* __restrict__ dinv, const float* __restrict__ b1,
                            float* __restrict__ hrelu, int N) {
  int gid = blockIdx.x * 256 + threadIdx.x;
  int n = gid >> 5, c4 = (gid & 31) * 4;  // 32 groups x 4 cols = 128
  if (n >= N) return;
  float di = dinv[n];
  float sl = di * di;
  float4 acc = *(const float4*)&h1[(size_t)n * HID + c4];
  acc.x *= sl; acc.y *= sl; acc.z *= sl; acc.w *= sl;
  int i = row_ptr[n];
  const int s1 = row_ptr[n + 1];
  for (; i + 4 <= s1; i += 4) {
    int j0 = eSrc[i], j1 = eSrc[i + 1], j2 = eSrc[i + 2], j3 = eSrc[i + 3];
    float w0 = eW[i], w1 = eW[i + 1], w2 = eW[i + 2], w3 = eW[i + 3];
    float4 v0 = *(const float4*)&h1[(size_t)j0 * HID + c4];
    float4 v1 = *(const float4*)&h1[(size_t)j1 * HID + c4];
    float4 v2 = *(const float4*)&h1[(size_t)j2 * HID + c4];
    float4 v3 = *(const float4*)&h1[(size_t)j3 * HID + c4];
    acc.x += w0 * v0.x + w1 * v1.x + w2 * v2.x + w3 * v3.x;
    acc.y += w0 * v0.y + w1 * v1.y + w2 * v2.y + w3 * v3.y;
    acc.z += w0 * v0.z + w1 * v1.z + w2 * v2.z + w3 * v3.z;
    acc.w += w0 * v0.w + w1 * v1.w + w2 * v2.w + w3 * v3.w;
  }
  for (; i < s1; i++) {
    int j = eSrc[i];
    float w = eW[i];
    float4 v = *(const float4*)&h1[(size_t)j * HID + c4];
    acc.x += w * v.x; acc.y += w * v.y; acc.z += w * v.z; acc.w += w * v.w;
  }
  float4 bb = *(const float4*)&b1[c4];
  float4 r;
  r.x = fmaxf(acc.x + bb.x, 0.f);
  r.y = fmaxf(acc.y + bb.y, 0.f);
  r.z = fmaxf(acc.z + bb.z, 0.f);
  r.w = fmaxf(acc.w + bb.w, 0.f);
  *(float4*)&hrelu[(size_t)n * HID + c4] = r;
}

// ---- GEMM2: H2[N,40] = hrelu[N,128] @ W2[128,40] ----
// block 256, 64 rows; W2 zero-padded to 48 cols in LDS for aligned float4 strips
__global__ __launch_bounds__(256) void gemm2_kernel(const float* __restrict__ A,
                                                    const float* __restrict__ W2,
                                                    float* __restrict__ H2, int N) {
  __shared__ float tA[64 * 129];   // pad 129: read bank = (row+k)%32 -> broadcast-only
  __shared__ float w2s[128 * 48];
  const int t = threadIdx.x;
  const int rowBase = blockIdx.x * 64;
  for (int idx = t; idx < 128 * 48; idx += 256) {
    int k = idx / 48, c = idx - k * 48;
    w2s[idx] = (c < OUTD) ? W2[k * OUTD + c] : 0.f;
  }
  for (int f = t; f < 2048; f += 256) {
    int row = f >> 5, c4 = (f & 31) * 4;
    float4 v = make_float4(0.f, 0.f, 0.f, 0.f);
    if (rowBase + row < N) v = *(const float4*)&A[(size_t)(rowBase + row) * HID + c4];
    tA[row * 129 + c4 + 0] = v.x;
    tA[row * 129 + c4 + 1] = v.y;
    tA[row * 129 + c4 + 2] = v.z;
    tA[row * 129 + c4 + 3] = v.w;
  }
  __syncthreads();
  const int row = t >> 2;          // 0..63 (4 lanes share a row -> LDS broadcast)
  const int c0 = (t & 3) * 12;     // 12-col strip
  float acc[12];
#pragma unroll
  for (int j = 0; j < 12; j++) acc[j] = 0.f;
  for (int k = 0; k < HID; k++) {
    float a = tA[row * 129 + k];
    const float* bp = &w2s[k * 48 + c0];
#pragma unroll
    for (int j = 0; j < 12; j++) acc[j] += a * bp[j];
  }
  int r = rowBase + row;
  if (r < N) {
#pragma unroll
    for (int j = 0; j < 12; j++) {
      int c = c0 + j;
      if (c < OUTD) H2[(size_t)r * OUTD + c] = acc[j];
    }
  }
}

// ---- agg2 v2: thread per (node, col-group-of-4) at 40 dims; float4 + 4-edge unroll ----
__global__ void agg2_kernel(const float* __restrict__ h2, const int* __restrict__ row_ptr,
                            const int* __restrict__ eSrc, const float* __restrict__ eW,
                            const float* __restrict__ dinv, const float* __restrict__ b2,
                            float* __restrict__ out, int N) {
  int gid = blockIdx.x * 256 + threadIdx.x;
  int n = gid / 10;                 // 10 groups x 4 cols = 40
  int c4 = (gid - n * 10) * 4;
  if (n >= N) return;
  float di = dinv[n];
  float sl = di * di;
  float4 acc = *(const float4*)&h2[(size_t)n * OUTD + c4];  // rows are 160B -> 16B-aligned
  acc.x *= sl; acc.y *= sl; acc.z *= sl; acc.w *= sl;
  int i = row_ptr[n];
  const int s1 = row_ptr[n + 1];
  for (; i + 4 <= s1; i += 4) {
    int j0 = eSrc[i], j1 = eSrc[i + 1], j2 = eSrc[i + 2], j3 = eSrc[i + 3];
    float w0 = eW[i], w1 = eW[i + 1], w2 = eW[i + 2], w3 = eW[i + 3];
    float4 v0 = *(const float4*)&h2[(size_t)j0 * OUTD + c4];
    float4 v1 = *(const float4*)&h2[(size_t)j1 * OUTD + c4];
    float4 v2 = *(const float4*)&h2[(size_t)j2 * OUTD + c4];
    float4 v3 = *(const float4*)&h2[(size_t)j3 * OUTD + c4];
    acc.x += w0 * v0.x + w1 * v1.x + w2 * v2.x + w3 * v3.x;
    acc.y += w0 * v0.y + w1 * v1.y + w2 * v2.y + w3 * v3.y;
    acc.z += w0 * v0.z + w1 * v1.z + w2 * v2.z + w3 * v3.z;
    acc.w += w0 * v0.w + w1 * v1.w + w2 * v2.w + w3 * v3.w;
  }
  for (; i < s1; i++) {
    int j = eSrc[i];
    float w = eW[i];
    float4 v = *(const float4*)&h2[(size_t)j * OUTD + c4];
    acc.x += w * v.x; acc.y += w * v.y; acc.z += w * v.z; acc.w += w * v.w;
  }
  float* o = &out[(size_t)n * OUTD + c4];
  o[0] = acc.x + b2[c4 + 0];
  o[1] = acc.y + b2[c4 + 1];
  o[2] = acc.z + b2[c4 + 2];
  o[3] = acc.w + b2[c4 + 3];
}

// ---- log_softmax over 40 cols, in place on d_out ----
__global__ void lsm_kernel(float* __restrict__ out, int N) {
  int n = blockIdx.x * 256 + threadIdx.x;
  if (n >= N) return;
  float* row = out + (size_t)n * OUTD;
  float v[OUTD];
  float m = -3.4e38f;
#pragma unroll
  for (int j = 0; j < OUTD; j++) {
    v[j] = row[j];
    m = fmaxf(m, v[j]);
  }
  float s = 0.f;
#pragma unroll
  for (int j = 0; j < OUTD; j++) s += expf(v[j] - m);
  float lse = m + logf(s);
#pragma unroll
  for (int j = 0; j < OUTD; j++) row[j] = v[j] - lse;
}

extern "C" void kernel_launch(void* const* d_in, const int* in_sizes, int n_in,
                              void* d_out, int out_size, void* d_ws, size_t ws_size,
                              hipStream_t stream) {
  const float* x  = (const float*)d_in[0];
  const int*   ei = (const int*)d_in[1];
  const float* W1 = (const float*)d_in[2];
  const float* b1 = (const float*)d_in[3];
  const float* W2 = (const float*)d_in[4];
  const float* b2 = (const float*)d_in[5];
  float* out = (float*)d_out;

  const int N = in_sizes[0] / IN_DIM;
  const int E = in_sizes[1] / 2;
  const int* src = ei;       // edge_index[0]
  const int* dst = ei + E;   // edge_index[1]

  // workspace layout (1KB-aligned): ~116 MB peak
  char* wsb = (char*)d_ws;
  size_t off = 0;
  auto alloc = [&](size_t bytes) -> char* {
    char* p = wsb + off;
    off = (off + bytes + 1023) & ~(size_t)1023;
    return p;
  };
  int*   deg       = (int*)alloc((size_t)N * 4);
  float* dinv      = (float*)alloc((size_t)N * 4);
  int*   blockSums = (int*)alloc(1024);
  int*   row_ptr   = (int*)alloc((size_t)(N + 1) * 4);
  int*   cursor    = (int*)alloc((size_t)N * 4);
  int*   eSrc      = (int*)alloc((size_t)E * 4);
  float* eW        = (float*)alloc((size_t)E * 4);
  float* h1        = (float*)alloc((size_t)N * HID * 4);
  float* hrelu     = (float*)alloc((size_t)N * HID * 4);
  float* h2        = h1;  // h1 dead after agg1; alias to cut peak ws usage
  (void)n_in; (void)out_size;

  // Workspace guard: if d_ws is too small, launching would OOB-write and
  // hard-crash the container. Bail (visible correctness failure) instead.
  if (off > ws_size) return;

  const int gE = (E + 255) / 256;
  const int gN = (N + 255) / 256;
  const int nb = (N + 1023) / 1024;
  const int gRows = (N + 63) / 64;

  zero_kernel<<<gN, 256, 0, stream>>>(deg, N);
  hist_kernel<<<gE, 256, 0, stream>>>(dst, deg, E);
  dinv_kernel<<<gN, 256, 0, stream>>>(deg, dinv, N);
  scan_a<<<nb, 256, 0, stream>>>(deg, row_ptr, blockSums, N);
  scan_b<<<1, 256, 0, stream>>>(blockSums, nb);
  scan_c<<<gN, 256, 0, stream>>>(row_ptr, blockSums, cursor, N, E);
  place_kernel<<<gE, 256, 0, stream>>>(src, dst, dinv, cursor, eSrc, eW, E);

  gemm1_kernel<<<gRows, 256, 0, stream>>>(x, W1, h1, N);
  agg1_kernel<<<(N * 32 + 255) / 256, 256, 0, stream>>>(h1, row_ptr, eSrc, eW, dinv, b1, hrelu, N);
  gemm2_kernel<<<gRows, 256, 0, stream>>>(hrelu, W2, h2, N);
  agg2_kernel<<<(N * 10 + 255) / 256, 256, 0, stream>>>(h2, row_ptr, eSrc, eW, dinv, b2, out, N);
  lsm_kernel<<<gN, 256, 0, stream>>>(out, N);
}

// Round 5
// 755.683 us; speedup vs baseline: 1.3833x; 1.1183x over previous
//
#include <hip/hip_runtime.h>
#include <hip/hip_bf16.h>

#define IN_DIM 500
#define HID 128
#define OUTD 40
#define KPAD 512

typedef __bf16 bf16x8 __attribute__((ext_vector_type(8)));
typedef float f32x16 __attribute__((ext_vector_type(16)));

static __device__ __forceinline__ float rsqrt_acc(float x) {
  float r = rsqrtf(x);
  return r * (1.5f - 0.5f * x * r * r);
}

static __device__ __forceinline__ unsigned short bf16_of(float f) {
  __bf16 h = (__bf16)f;
  return __builtin_bit_cast(unsigned short, h);
}
static __device__ __forceinline__ float bf16_back(unsigned short u) {
  return (float)__builtin_bit_cast(__bf16, u);
}

// ---- zero-fill (graph-capture-safe) ----
__global__ void zero_kernel(int* __restrict__ p, int n) {
  int i = blockIdx.x * 256 + threadIdx.x;
  if (i < n) p[i] = 0;
}

// ---- degree histogram over dst ----
__global__ void hist_kernel(const int* __restrict__ dst, int* __restrict__ deg, int E) {
  int e = blockIdx.x * 256 + threadIdx.x;
  if (e < E) atomicAdd(&deg[dst[e]], 1);
}

__global__ void dinv_kernel(const int* __restrict__ deg, float* __restrict__ dinv, int N) {
  int n = blockIdx.x * 256 + threadIdx.x;
  if (n < N) dinv[n] = rsqrt_acc((float)deg[n] + 1.0f);
}

// ---- two-level exclusive scan of deg -> row_ptr ----
__global__ void scan_a(const int* __restrict__ deg, int* __restrict__ partial,
                       int* __restrict__ blockSums, int N) {
  __shared__ int sums[256];
  int t = threadIdx.x;
  int base = blockIdx.x * 1024 + t * 4;
  int v0 = (base + 0) < N ? deg[base + 0] : 0;
  int v1 = (base + 1) < N ? deg[base + 1] : 0;
  int v2 = (base + 2) < N ? deg[base + 2] : 0;
  int v3 = (base + 3) < N ? deg[base + 3] : 0;
  int l0 = v0, l1 = l0 + v1, l2 = l1 + v2, l3 = l2 + v3;
  sums[t] = l3;
  __syncthreads();
  for (int o = 1; o < 256; o <<= 1) {
    int a = sums[t];
    int b = (t >= o) ? sums[t - o] : 0;
    __syncthreads();
    sums[t] = a + b;
    __syncthreads();
  }
  int excl = sums[t] - l3;
  if (t == 0) blockSums[blockIdx.x] = sums[255];
  if (base + 0 < N) partial[base + 0] = excl;
  if (base + 1 < N) partial[base + 1] = excl + l0;
  if (base + 2 < N) partial[base + 2] = excl + l1;
  if (base + 3 < N) partial[base + 3] = excl + l2;
}

__global__ void scan_b(int* __restrict__ blockSums, int nb) {
  __shared__ int s[256];
  int t = threadIdx.x;
  int orig = (t < nb) ? blockSums[t] : 0;
  s[t] = orig;
  __syncthreads();
  for (int o = 1; o < 256; o <<= 1) {
    int a = s[t];
    int b = (t >= o) ? s[t - o] : 0;
    __syncthreads();
    s[t] = a + b;
    __syncthreads();
  }
  if (t < nb) blockSums[t] = s[t] - orig;
}

__global__ void scan_c(int* __restrict__ row_ptr, const int* __restrict__ blockOff,
                       int* __restrict__ cursor, int N, int E) {
  int n = blockIdx.x * 256 + threadIdx.x;
  if (n < N) {
    int v = row_ptr[n] + blockOff[n >> 10];
    row_ptr[n] = v;
    cursor[n] = v;
  }
  if (n == 0 && blockIdx.x == 0) row_ptr[N] = E;
}

// ---- CSR placement ----
__global__ void place_kernel(const int* __restrict__ src, const int* __restrict__ dst,
                             const float* __restrict__ dinv, int* __restrict__ cursor,
                             int* __restrict__ eSrc, float* __restrict__ eW, int E) {
  int e = blockIdx.x * 256 + threadIdx.x;
  if (e < E) {
    int s = src[e], d = dst[e];
    int pos = atomicAdd(&cursor[d], 1);
    eSrc[pos] = s;
    eW[pos] = dinv[s] * dinv[d];
  }
}

// ---- W1 -> transposed, K-padded, split hi/lo bf16 (once per call, tiny) ----
__global__ void convW1_kernel(const float* __restrict__ W1, unsigned short* __restrict__ Whi,
                              unsigned short* __restrict__ Wlo) {
  int idx = blockIdx.x * 256 + threadIdx.x;   // 128*512
  if (idx >= HID * KPAD) return;
  int n = idx >> 9, k = idx & (KPAD - 1);
  float f = (k < IN_DIM) ? W1[(size_t)k * HID + n] : 0.f;
  unsigned short h = bf16_of(f);
  Whi[idx] = h;
  Wlo[idx] = bf16_of(f - bf16_back(h));
}

// ---- GEMM1 (MFMA): H1[N,128] = X[N,500] @ W1 via split-bf16 3-product ----
// block = 256 thr (4 waves); tile 128 rows x 128 cols; K chunk 32 (16 rounds).
// LDS stride 40 bf16 = 80 B: 16B-aligned ds_read_b128, perfectly bank-balanced.
#define LSTR 40
__global__ __launch_bounds__(256) void gemm1_kernel(const float* __restrict__ X,
                                                    const unsigned short* __restrict__ Whi,
                                                    const unsigned short* __restrict__ Wlo,
                                                    float* __restrict__ H1, int N) {
  __shared__ unsigned short sAhi[128 * LSTR];
  __shared__ unsigned short sAlo[128 * LSTR];
  __shared__ unsigned short sBhi[128 * LSTR];
  __shared__ unsigned short sBlo[128 * LSTR];
  const int t = threadIdx.x;
  const int rowBase = blockIdx.x * 128;
  const int lane = t & 63;
  const int w = t >> 6;          // wave id: rows w*32..+32
  const int m = lane & 31;
  const int quad = lane >> 5;    // k-offset quad*8

  f32x16 acc[4];
#pragma unroll
  for (int i = 0; i < 4; i++) acc[i] = (f32x16)(0.f);

  // staging assignments: thread covers 16 elements (half a row) per round
  const int srow = t >> 1;             // 0..127
  const int skoff = (t & 1) * 16;      // 0 / 16
  const bool rok = (rowBase + srow) < N;
  const float* xrow = X + (size_t)(rowBase + (rok ? srow : 0)) * IN_DIM;

  for (int k0 = 0; k0 < KPAD; k0 += 32) {
    __syncthreads();   // protect LDS reuse from previous round's readers
    // ---- stage A: fp32 -> hi/lo bf16 ----
    {
      float f[16];
      if (rok && (k0 + skoff + 16) <= IN_DIM) {
        const float4* p = (const float4*)(xrow + k0 + skoff);
        float4 v0 = p[0], v1 = p[1], v2 = p[2], v3 = p[3];
        f[0]=v0.x; f[1]=v0.y; f[2]=v0.z; f[3]=v0.w;
        f[4]=v1.x; f[5]=v1.y; f[6]=v1.z; f[7]=v1.w;
        f[8]=v2.x; f[9]=v2.y; f[10]=v2.z; f[11]=v2.w;
        f[12]=v3.x; f[13]=v3.y; f[14]=v3.z; f[15]=v3.w;
      } else {
#pragma unroll
        for (int j = 0; j < 16; j++) {
          int k = k0 + skoff + j;
          f[j] = (rok && k < IN_DIM) ? xrow[k] : 0.f;
        }
      }
#pragma unroll
      for (int g = 0; g < 4; g++) {
        ushort4 h, l;
        h.x = bf16_of(f[g*4+0]); l.x = bf16_of(f[g*4+0] - bf16_back(h.x));
        h.y = bf16_of(f[g*4+1]); l.y = bf16_of(f[g*4+1] - bf16_back(h.y));
        h.z = bf16_of(f[g*4+2]); l.z = bf16_of(f[g*4+2] - bf16_back(h.z));
        h.w = bf16_of(f[g*4+3]); l.w = bf16_of(f[g*4+3] - bf16_back(h.w));
        *(ushort4*)&sAhi[srow * LSTR + skoff + g * 4] = h;
        *(ushort4*)&sAlo[srow * LSTR + skoff + g * 4] = l;
      }
    }
    // ---- stage B: precomputed bf16 hi/lo (B^T layout [n][k]) ----
    {
      const int n = srow;            // 0..127
      const size_t gb = (size_t)n * KPAD + k0 + skoff;
      uint4 h0 = *(const uint4*)&Whi[gb];       // 8 bf16
      uint4 h1v = *(const uint4*)&Whi[gb + 8];
      uint4 l0 = *(const uint4*)&Wlo[gb];
      uint4 l1 = *(const uint4*)&Wlo[gb + 8];
      *(uint4*)&sBhi[n * LSTR + skoff] = h0;
      *(uint4*)&sBhi[n * LSTR + skoff + 8] = h1v;
      *(uint4*)&sBlo[n * LSTR + skoff] = l0;
      *(uint4*)&sBlo[n * LSTR + skoff + 8] = l1;
    }
    __syncthreads();

    // ---- compute: 2 k16 substeps x 4 n-tiles x 3 mfma ----
#pragma unroll
    for (int sub = 0; sub < 2; sub++) {
      const int ks = sub * 16 + quad * 8;
      bf16x8 ah = *(const bf16x8*)&sAhi[(w * 32 + m) * LSTR + ks];
      bf16x8 al = *(const bf16x8*)&sAlo[(w * 32 + m) * LSTR + ks];
#pragma unroll
      for (int nt = 0; nt < 4; nt++) {
        bf16x8 bh = *(const bf16x8*)&sBhi[(nt * 32 + m) * LSTR + ks];
        bf16x8 bl = *(const bf16x8*)&sBlo[(nt * 32 + m) * LSTR + ks];
        acc[nt] = __builtin_amdgcn_mfma_f32_32x32x16_bf16(ah, bh, acc[nt], 0, 0, 0);
        acc[nt] = __builtin_amdgcn_mfma_f32_32x32x16_bf16(ah, bl, acc[nt], 0, 0, 0);
        acc[nt] = __builtin_amdgcn_mfma_f32_32x32x16_bf16(al, bh, acc[nt], 0, 0, 0);
      }
    }
  }

  // ---- epilogue: C/D layout col=lane&31, row=(reg&3)+8*(reg>>2)+4*quad ----
#pragma unroll
  for (int nt = 0; nt < 4; nt++) {
#pragma unroll
    for (int r = 0; r < 16; r++) {
      int rowin = (r & 3) + 8 * (r >> 2) + 4 * quad;
      int grow = rowBase + w * 32 + rowin;
      if (grow < N) H1[(size_t)grow * HID + nt * 32 + m] = acc[nt][r];
    }
  }
}

// ---- agg1: thread per (node, col-group-of-4); float4 gather, 4-edge unroll ----
__global__ void agg1_kernel(const float* __restrict__ h1, const int* __restrict__ row_ptr,
                            const int* __restrict__ eSrc, const float* __restrict__ eW,
                            const float* __restrict__ dinv, const float* __restrict__ b1,
                            float* __restrict__ hrelu, int N) {
  int gid = blockIdx.x * 256 + threadIdx.x;
  int n = gid >> 5, c4 = (gid & 31) * 4;
  if (n >= N) return;
  float di = dinv[n];
  float sl = di * di;
  float4 acc = *(const float4*)&h1[(size_t)n * HID + c4];
  acc.x *= sl; acc.y *= sl; acc.z *= sl; acc.w *= sl;
  int i = row_ptr[n];
  const int s1 = row_ptr[n + 1];
  for (; i + 4 <= s1; i += 4) {
    int j0 = eSrc[i], j1 = eSrc[i + 1], j2 = eSrc[i + 2], j3 = eSrc[i + 3];
    float w0 = eW[i], w1 = eW[i + 1], w2 = eW[i + 2], w3 = eW[i + 3];
    float4 v0 = *(const float4*)&h1[(size_t)j0 * HID + c4];
    float4 v1 = *(const float4*)&h1[(size_t)j1 * HID + c4];
    float4 v2 = *(const float4*)&h1[(size_t)j2 * HID + c4];
    float4 v3 = *(const float4*)&h1[(size_t)j3 * HID + c4];
    acc.x += w0 * v0.x + w1 * v1.x + w2 * v2.x + w3 * v3.x;
    acc.y += w0 * v0.y + w1 * v1.y + w2 * v2.y + w3 * v3.y;
    acc.z += w0 * v0.z + w1 * v1.z + w2 * v2.z + w3 * v3.z;
    acc.w += w0 * v0.w + w1 * v1.w + w2 * v2.w + w3 * v3.w;
  }
  for (; i < s1; i++) {
    int j = eSrc[i];
    float w = eW[i];
    float4 v = *(const float4*)&h1[(size_t)j * HID + c4];
    acc.x += w * v.x; acc.y += w * v.y; acc.z += w * v.z; acc.w += w * v.w;
  }
  float4 bb = *(const float4*)&b1[c4];
  float4 r;
  r.x = fmaxf(acc.x + bb.x, 0.f);
  r.y = fmaxf(acc.y + bb.y, 0.f);
  r.z = fmaxf(acc.z + bb.z, 0.f);
  r.w = fmaxf(acc.w + bb.w, 0.f);
  *(float4*)&hrelu[(size_t)n * HID + c4] = r;
}

// ---- GEMM2: H2[N,40] = hrelu[N,128] @ W2[128,40] ----
__global__ __launch_bounds__(256) void gemm2_kernel(const float* __restrict__ A,
                                                    const float* __restrict__ W2,
                                                    float* __restrict__ H2, int N) {
  __shared__ float tA[64 * 129];
  __shared__ float w2s[128 * 48];
  const int t = threadIdx.x;
  const int rowBase = blockIdx.x * 64;
  for (int idx = t; idx < 128 * 48; idx += 256) {
    int k = idx / 48, c = idx - k * 48;
    w2s[idx] = (c < OUTD) ? W2[k * OUTD + c] : 0.f;
  }
  for (int f = t; f < 2048; f += 256) {
    int row = f >> 5, c4 = (f & 31) * 4;
    float4 v = make_float4(0.f, 0.f, 0.f, 0.f);
    if (rowBase + row < N) v = *(const float4*)&A[(size_t)(rowBase + row) * HID + c4];
    tA[row * 129 + c4 + 0] = v.x;
    tA[row * 129 + c4 + 1] = v.y;
    tA[row * 129 + c4 + 2] = v.z;
    tA[row * 129 + c4 + 3] = v.w;
  }
  __syncthreads();
  const int row = t >> 2;
  const int c0 = (t & 3) * 12;
  float acc[12];
#pragma unroll
  for (int j = 0; j < 12; j++) acc[j] = 0.f;
  for (int k = 0; k < HID; k++) {
    float a = tA[row * 129 + k];
    const float* bp = &w2s[k * 48 + c0];
#pragma unroll
    for (int j = 0; j < 12; j++) acc[j] += a * bp[j];
  }
  int r = rowBase + row;
  if (r < N) {
#pragma unroll
    for (int j = 0; j < 12; j++) {
      int c = c0 + j;
      if (c < OUTD) H2[(size_t)r * OUTD + c] = acc[j];
    }
  }
}

// ---- agg2: thread per (node, col-group-of-4) at 40 dims ----
__global__ void agg2_kernel(const float* __restrict__ h2, const int* __restrict__ row_ptr,
                            const int* __restrict__ eSrc, const float* __restrict__ eW,
                            const float* __restrict__ dinv, const float* __restrict__ b2,
                            float* __restrict__ out, int N) {
  int gid = blockIdx.x * 256 + threadIdx.x;
  int n = gid / 10;
  int c4 = (gid - n * 10) * 4;
  if (n >= N) return;
  float di = dinv[n];
  float sl = di * di;
  float4 acc = *(const float4*)&h2[(size_t)n * OUTD + c4];
  acc.x *= sl; acc.y *= sl; acc.z *= sl; acc.w *= sl;
  int i = row_ptr[n];
  const int s1 = row_ptr[n + 1];
  for (; i + 4 <= s1; i += 4) {
    int j0 = eSrc[i], j1 = eSrc[i + 1], j2 = eSrc[i + 2], j3 = eSrc[i + 3];
    float w0 = eW[i], w1 = eW[i + 1], w2 = eW[i + 2], w3 = eW[i + 3];
    float4 v0 = *(const float4*)&h2[(size_t)j0 * OUTD + c4];
    float4 v1 = *(const float4*)&h2[(size_t)j1 * OUTD + c4];
    float4 v2 = *(const float4*)&h2[(size_t)j2 * OUTD + c4];
    float4 v3 = *(const float4*)&h2[(size_t)j3 * OUTD + c4];
    acc.x += w0 * v0.x + w1 * v1.x + w2 * v2.x + w3 * v3.x;
    acc.y += w0 * v0.y + w1 * v1.y + w2 * v2.y + w3 * v3.y;
    acc.z += w0 * v0.z + w1 * v1.z + w2 * v2.z + w3 * v3.z;
    acc.w += w0 * v0.w + w1 * v1.w + w2 * v2.w + w3 * v3.w;
  }
  for (; i < s1; i++) {
    int j = eSrc[i];
    float w = eW[i];
    float4 v = *(const float4*)&h2[(size_t)j * OUTD + c4];
    acc.x += w * v.x; acc.y += w * v.y; acc.z += w * v.z; acc.w += w * v.w;
  }
  float* o = &out[(size_t)n * OUTD + c4];
  o[0] = acc.x + b2[c4 + 0];
  o[1] = acc.y + b2[c4 + 1];
  o[2] = acc.z + b2[c4 + 2];
  o[3] = acc.w + b2[c4 + 3];
}

// ---- log_softmax over 40 cols ----
__global__ void lsm_kernel(float* __restrict__ out, int N) {
  int n = blockIdx.x * 256 + threadIdx.x;
  if (n >= N) return;
  float* row = out + (size_t)n * OUTD;
  float v[OUTD];
  float m = -3.4e38f;
#pragma unroll
  for (int j = 0; j < OUTD; j++) {
    v[j] = row[j];
    m = fmaxf(m, v[j]);
  }
  float s = 0.f;
#pragma unroll
  for (int j = 0; j < OUTD; j++) s += expf(v[j] - m);
  float lse = m + logf(s);
#pragma unroll
  for (int j = 0; j < OUTD; j++) row[j] = v[j] - lse;
}

extern "C" void kernel_launch(void* const* d_in, const int* in_sizes, int n_in,
                              void* d_out, int out_size, void* d_ws, size_t ws_size,
                              hipStream_t stream) {
  const float* x  = (const float*)d_in[0];
  const int*   ei = (const int*)d_in[1];
  const float* W1 = (const float*)d_in[2];
  const float* b1 = (const float*)d_in[3];
  const float* W2 = (const float*)d_in[4];
  const float* b2 = (const float*)d_in[5];
  float* out = (float*)d_out;

  const int N = in_sizes[0] / IN_DIM;
  const int E = in_sizes[1] / 2;
  const int* src = ei;
  const int* dst = ei + E;

  char* wsb = (char*)d_ws;
  size_t off = 0;
  auto alloc = [&](size_t bytes) -> char* {
    char* p = wsb + off;
    off = (off + bytes + 1023) & ~(size_t)1023;
    return p;
  };
  int*   deg       = (int*)alloc((size_t)N * 4);
  float* dinv      = (float*)alloc((size_t)N * 4);
  int*   blockSums = (int*)alloc(1024);
  int*   row_ptr   = (int*)alloc((size_t)(N + 1) * 4);
  int*   cursor    = (int*)alloc((size_t)N * 4);
  int*   eSrc      = (int*)alloc((size_t)E * 4);
  float* eW        = (float*)alloc((size_t)E * 4);
  unsigned short* Whi = (unsigned short*)alloc((size_t)HID * KPAD * 2);
  unsigned short* Wlo = (unsigned short*)alloc((size_t)HID * KPAD * 2);
  float* h1        = (float*)alloc((size_t)N * HID * 4);
  float* hrelu     = (float*)alloc((size_t)N * HID * 4);
  float* h2        = h1;  // h1 dead after agg1
  (void)n_in; (void)out_size;

  if (off > ws_size) return;  // visible failure instead of OOB crash

  const int gE = (E + 255) / 256;
  const int gN = (N + 255) / 256;
  const int nb = (N + 1023) / 1024;

  zero_kernel<<<gN, 256, 0, stream>>>(deg, N);
  hist_kernel<<<gE, 256, 0, stream>>>(dst, deg, E);
  dinv_kernel<<<gN, 256, 0, stream>>>(deg, dinv, N);
  scan_a<<<nb, 256, 0, stream>>>(deg, row_ptr, blockSums, N);
  scan_b<<<1, 256, 0, stream>>>(blockSums, nb);
  scan_c<<<gN, 256, 0, stream>>>(row_ptr, blockSums, cursor, N, E);
  place_kernel<<<gE, 256, 0, stream>>>(src, dst, dinv, cursor, eSrc, eW, E);
  convW1_kernel<<<(HID * KPAD + 255) / 256, 256, 0, stream>>>(W1, Whi, Wlo);

  gemm1_kernel<<<(N + 127) / 128, 256, 0, stream>>>(x, Whi, Wlo, h1, N);
  agg1_kernel<<<(N * 32 + 255) / 256, 256, 0, stream>>>(h1, row_ptr, eSrc, eW, dinv, b1, hrelu, N);
  gemm2_kernel<<<(N + 63) / 64, 256, 0, stream>>>(hrelu, W2, h2, N);
  agg2_kernel<<<(N * 10 + 255) / 256, 256, 0, stream>>>(h2, row_ptr, eSrc, eW, dinv, b2, out, N);
  lsm_kernel<<<gN, 256, 0, stream>>>(out, N);
}